// Round 2
// baseline (48.643 us; speedup 1.0000x reference)
//
#include <hip/hip_runtime.h>

#define G_ 1024
#define DIN_ 3072
#define B_ 8192
#define TB 4
#define TPB 1024

// ---------------------------------------------------------------------------
// Kernel 1: per-group parameter precompute.
// out[b,g,m] = K + cx0*x0 + cx1*x1 + cx2*x2 + cq01*x0x1 + cq02*x0x2 + cq12*x1x2
// (gating + softmax + all 6 permutations folded into 7 coeffs per (g,m)).
// Packed record per group: 32 floats (128 B, one cache line):
//   [0..2]  conn indices (int bits), [3] pad
//   [4+8m .. 10+8m]  K, cx0, cx1, cx2, cq01, cq02, cq12   (m = 0..2), [+7] pad
// ---------------------------------------------------------------------------
__global__ __launch_bounds__(256) void fredkin_coef_kernel(
    const int* __restrict__ conn, const float* __restrict__ sel,
    const float* __restrict__ wg, float* __restrict__ cw)
{
    int g = blockIdx.x * blockDim.x + threadIdx.x;
    if (g >= G_) return;

    float u[3], v[3];
#pragma unroll
    for (int i = 0; i < 3; ++i) {
        float s = sel[g * 3 + i];
        float C = s / (1.0f + fabsf(s));
        float a = fabsf(C);
        u[i] = 1.0f - a;          // multiplier on x
        v[i] = 0.5f * (C + a);    // additive bias
    }

    // softmax over the 6 permutation weights
    float w[6];
    float mx = -1e30f;
#pragma unroll
    for (int p = 0; p < 6; ++p) mx = fmaxf(mx, wg[g * 6 + p]);
    float sum = 0.0f;
#pragma unroll
    for (int p = 0; p < 6; ++p) { w[p] = expf(wg[g * 6 + p] - mx); sum += w[p]; }
    float inv = 1.0f / sum;
#pragma unroll
    for (int p = 0; p < 6; ++p) w[p] *= inv;

    // itertools.permutations(range(3)) order
    const int P[6][3] = {{0,1,2},{0,2,1},{1,0,2},{1,2,0},{2,0,1},{2,1,0}};
    // signal_0 = a ; signal_1 = c + ab - ac ; signal_2 = b - ab + ac
    // L[m][i]: coeff on gated_i ; Q[m][pair]: coeff on gated_i*gated_j,
    // pair index (0,1)->0 (0,2)->1 (1,2)->2  (== i+j-1 for i<j)
    float L[3][3] = {{0.f,0.f,0.f},{0.f,0.f,0.f},{0.f,0.f,0.f}};
    float Q[3][3] = {{0.f,0.f,0.f},{0.f,0.f,0.f},{0.f,0.f,0.f}};
#pragma unroll
    for (int p = 0; p < 6; ++p) {
        int i0 = P[p][0], i1 = P[p][1], i2 = P[p][2];
        float wp = w[p];
        int p01 = i0 + i1 - 1;
        int p02 = i0 + i2 - 1;
        L[0][i0] += wp;                                   // m0
        L[1][i2] += wp; Q[1][p01] += wp; Q[1][p02] -= wp; // m1
        L[2][i1] += wp; Q[2][p01] -= wp; Q[2][p02] += wp; // m2
    }

    float* o = cw + (size_t)g * 32;
    int* oi = (int*)o;
    oi[0] = conn[g * 3 + 0];
    oi[1] = conn[g * 3 + 1];
    oi[2] = conn[g * 3 + 2];
    oi[3] = 0;

    // substitute gated_i = u_i*x_i + v_i  ->  x-space coefficients
#pragma unroll
    for (int m = 0; m < 3; ++m) {
        float K = L[m][0]*v[0] + L[m][1]*v[1] + L[m][2]*v[2]
                + Q[m][0]*v[0]*v[1] + Q[m][1]*v[0]*v[2] + Q[m][2]*v[1]*v[2];
        float cx0 = u[0]*(L[m][0] + Q[m][0]*v[1] + Q[m][1]*v[2]);
        float cx1 = u[1]*(L[m][1] + Q[m][0]*v[0] + Q[m][2]*v[2]);
        float cx2 = u[2]*(L[m][2] + Q[m][1]*v[0] + Q[m][2]*v[1]);
        float* om = o + 4 + m * 8;
        om[0]=K; om[1]=cx0; om[2]=cx1; om[3]=cx2;
        om[4]=Q[m][0]*u[0]*u[1]; om[5]=Q[m][1]*u[0]*u[2]; om[6]=Q[m][2]*u[1]*u[2];
        om[7]=0.f;
    }
}

// ---------------------------------------------------------------------------
// Kernel 2: streaming evaluation. 1024 threads/block, thread t owns group t.
// TB=4 rows of x staged in 48 KiB LDS (coalesced float4). VGPR ~60, so
// 2 blocks/CU = 32 waves/CU (full occupancy). Group params = one 128 B line,
// loaded before the staging barrier so L2 latency overlaps the tile load.
// ---------------------------------------------------------------------------
__global__ __launch_bounds__(1024) void fredkin_main_kernel(
    const float* __restrict__ x, const float* __restrict__ cw,
    float* __restrict__ out)
{
    __shared__ float xs[TB * DIN_];   // 48 KiB
    const int t = threadIdx.x;        // group id
    const int row0 = blockIdx.x * TB;

    // group params (issued first; latency hides under the staging loads)
    const float4* cf = (const float4*)(cw + (size_t)t * 32);
    const int4 cc = ((const int4*)cf)[0];
    const float4 a0 = cf[1], q0 = cf[2];
    const float4 a1 = cf[3], q1 = cf[4];
    const float4 a2 = cf[5], q2 = cf[6];
    const int c0 = cc.x, c1 = cc.y, c2 = cc.z;

    // stage TB rows, coalesced
    const float4* xv = (const float4*)(x + (size_t)row0 * DIN_);
    float4* sv = (float4*)xs;
#pragma unroll
    for (int i = 0; i < (TB * DIN_ / 4) / TPB; ++i)   // 3 iters
        sv[t + i * TPB] = xv[t + i * TPB];
    __syncthreads();

    // gather all rows first: 12 independent LDS reads in flight
    float g0[TB], g1[TB], g2[TB];
#pragma unroll
    for (int r = 0; r < TB; ++r) {
        g0[r] = xs[r * DIN_ + c0];
        g1[r] = xs[r * DIN_ + c1];
        g2[r] = xs[r * DIN_ + c2];
    }
#pragma unroll
    for (int r = 0; r < TB; ++r) {
        const float x0 = g0[r], x1 = g1[r], x2 = g2[r];
        const float p01 = x0 * x1, p02 = x0 * x2, p12 = x1 * x2;
        float o0 = a0.x + a0.y*x0 + a0.z*x1 + a0.w*x2 + q0.x*p01 + q0.y*p02 + q0.z*p12;
        float o1 = a1.x + a1.y*x0 + a1.z*x1 + a1.w*x2 + q1.x*p01 + q1.y*p02 + q1.z*p12;
        float o2 = a2.x + a2.y*x0 + a2.z*x1 + a2.w*x2 + q2.x*p01 + q2.y*p02 + q2.z*p12;
        const size_t off = (size_t)(row0 + r) * (3 * G_) + 3 * t;
        out[off + 0] = o0;
        out[off + 1] = o1;
        out[off + 2] = o2;
    }
}

extern "C" void kernel_launch(void* const* d_in, const int* in_sizes, int n_in,
                              void* d_out, int out_size, void* d_ws, size_t ws_size,
                              hipStream_t stream) {
    const float* x    = (const float*)d_in[0];
    const int*   conn = (const int*)d_in[1];
    const float* sel  = (const float*)d_in[2];
    const float* wg   = (const float*)d_in[3];
    float* out = (float*)d_out;
    float* cw  = (float*)d_ws;   // G_*32 floats = 128 KiB

    hipLaunchKernelGGL(fredkin_coef_kernel, dim3(G_ / 256), dim3(256), 0, stream,
                       conn, sel, wg, cw);
    hipLaunchKernelGGL(fredkin_main_kernel, dim3(B_ / TB), dim3(TPB), 0, stream,
                       x, cw, out);
}

// Round 3
// 43.044 us; speedup vs baseline: 1.1301x; 1.1301x over previous
//
#include <hip/hip_runtime.h>

#define G_ 1024
#define DIN_ 3072
#define B_ 8192
#define TB 4          // rows per tile (48 KiB LDS)
#define RT 2          // row-tiles per block (persistence)
#define TPB 256

// ---------------------------------------------------------------------------
// Kernel 1: per-group coefficient precompute.
// out[b,g,m] = K + cx0*x0 + cx1*x1 + cx2*x2 + cq01*x0x1 + cq02*x0x2 + cq12*x1x2
// (gating + softmax + all 6 permutations folded into 7 coeffs per (g,m)).
// coef layout: coef[g*24 + m*8 + {0..6}]  (float4-friendly stride 8)
// ---------------------------------------------------------------------------
__global__ __launch_bounds__(256) void fredkin_coef_kernel(
    const int* __restrict__ conn, const float* __restrict__ sel,
    const float* __restrict__ wg, float* __restrict__ coef)
{
    int g = blockIdx.x * blockDim.x + threadIdx.x;
    if (g >= G_) return;

    float u[3], v[3];
#pragma unroll
    for (int i = 0; i < 3; ++i) {
        float s = sel[g * 3 + i];
        float C = s / (1.0f + fabsf(s));
        float a = fabsf(C);
        u[i] = 1.0f - a;          // multiplier on x
        v[i] = 0.5f * (C + a);    // additive bias
    }

    float w[6];
    float mx = -1e30f;
#pragma unroll
    for (int p = 0; p < 6; ++p) mx = fmaxf(mx, wg[g * 6 + p]);
    float sum = 0.0f;
#pragma unroll
    for (int p = 0; p < 6; ++p) { w[p] = expf(wg[g * 6 + p] - mx); sum += w[p]; }
    float inv = 1.0f / sum;
#pragma unroll
    for (int p = 0; p < 6; ++p) w[p] *= inv;

    // itertools.permutations(range(3)) order
    const int P[6][3] = {{0,1,2},{0,2,1},{1,0,2},{1,2,0},{2,0,1},{2,1,0}};
    // signal_0 = a ; signal_1 = c + ab - ac ; signal_2 = b - ab + ac
    float L[3][3] = {{0.f,0.f,0.f},{0.f,0.f,0.f},{0.f,0.f,0.f}};
    float Q[3][3] = {{0.f,0.f,0.f},{0.f,0.f,0.f},{0.f,0.f,0.f}};
#pragma unroll
    for (int p = 0; p < 6; ++p) {
        int i0 = P[p][0], i1 = P[p][1], i2 = P[p][2];
        float wp = w[p];
        int p01 = i0 + i1 - 1;   // pair idx (i,j)->i+j-1 for i<j
        int p02 = i0 + i2 - 1;
        L[0][i0] += wp;                                   // m0
        L[1][i2] += wp; Q[1][p01] += wp; Q[1][p02] -= wp; // m1
        L[2][i1] += wp; Q[2][p01] -= wp; Q[2][p02] += wp; // m2
    }

#pragma unroll
    for (int m = 0; m < 3; ++m) {
        float K = L[m][0]*v[0] + L[m][1]*v[1] + L[m][2]*v[2]
                + Q[m][0]*v[0]*v[1] + Q[m][1]*v[0]*v[2] + Q[m][2]*v[1]*v[2];
        float cx0 = u[0]*(L[m][0] + Q[m][0]*v[1] + Q[m][1]*v[2]);
        float cx1 = u[1]*(L[m][1] + Q[m][0]*v[0] + Q[m][2]*v[2]);
        float cx2 = u[2]*(L[m][2] + Q[m][1]*v[0] + Q[m][2]*v[1]);
        float* om = coef + (size_t)g * 24 + m * 8;
        om[0]=K; om[1]=cx0; om[2]=cx1; om[3]=cx2;
        om[4]=Q[m][0]*u[0]*u[1]; om[5]=Q[m][1]*u[0]*u[2]; om[6]=Q[m][2]*u[1]*u[2];
        om[7]=0.f;
    }
}

// ---------------------------------------------------------------------------
// Kernel 2: persistent streaming evaluation.
// 256 threads/block, thread t owns groups {t, t+256, t+512, t+768}.
// Block processes RT=2 row-tiles of TB=4 rows; conn indices live in regs for
// the whole block (loaded pre-barrier, once). x staged direct-to-LDS via
// global_load_lds width=16 (no VGPR round-trip; loads drain at the barrier).
// ---------------------------------------------------------------------------
__global__ __launch_bounds__(TPB) void fredkin_main_kernel(
    const float* __restrict__ x, const int* __restrict__ conn,
    const float* __restrict__ coef, float* __restrict__ out)
{
    __shared__ float xs[TB * DIN_];   // 48 KiB -> 3 blocks/CU
    const int t = threadIdx.x;

    // conn indices for this thread's 4 groups: loaded ONCE per block,
    // issued before any staging so the gather chain is never cold.
    int c0[4], c1[4], c2[4];
#pragma unroll
    for (int gi = 0; gi < 4; ++gi) {
        const int g = t + gi * TPB;
        c0[gi] = conn[g * 3 + 0];
        c1[gi] = conn[g * 3 + 1];
        c2[gi] = conn[g * 3 + 2];
    }

    for (int tile = 0; tile < RT; ++tile) {
        const int row0 = (blockIdx.x * RT + tile) * TB;
        if (tile) __syncthreads();    // LDS overwrite guard

        // stage TB rows direct-to-LDS, 12 x 16B per thread, coalesced.
        // lds dest is wave-uniform base + lane*16 (linear layout) -- valid.
        const float4* xv = (const float4*)(x + (size_t)row0 * DIN_);
        float4* sv = (float4*)xs;
#pragma unroll
        for (int i = 0; i < (TB * DIN_ / 4) / TPB; ++i) {  // 12 iters
            __builtin_amdgcn_global_load_lds(
                (const __attribute__((address_space(1))) void*)(xv + t + i * TPB),
                (__attribute__((address_space(3))) void*)(sv + t + i * TPB),
                16, 0, 0);
        }
        __syncthreads();

#pragma unroll 2
        for (int gi = 0; gi < 4; ++gi) {
            const int g = t + gi * TPB;
            const float4* cf = (const float4*)(coef + (size_t)g * 24);
            const float4 a0 = cf[0], q0 = cf[1];
            const float4 a1 = cf[2], q1 = cf[3];
            const float4 a2 = cf[4], q2 = cf[5];
            // all 12 gathers independent, issued together
            float g0[TB], g1[TB], g2[TB];
#pragma unroll
            for (int r = 0; r < TB; ++r) {
                g0[r] = xs[r * DIN_ + c0[gi]];
                g1[r] = xs[r * DIN_ + c1[gi]];
                g2[r] = xs[r * DIN_ + c2[gi]];
            }
#pragma unroll
            for (int r = 0; r < TB; ++r) {
                const float x0 = g0[r], x1 = g1[r], x2 = g2[r];
                const float p01 = x0 * x1, p02 = x0 * x2, p12 = x1 * x2;
                float o0 = a0.x + a0.y*x0 + a0.z*x1 + a0.w*x2 + q0.x*p01 + q0.y*p02 + q0.z*p12;
                float o1 = a1.x + a1.y*x0 + a1.z*x1 + a1.w*x2 + q1.x*p01 + q1.y*p02 + q1.z*p12;
                float o2 = a2.x + a2.y*x0 + a2.z*x1 + a2.w*x2 + q2.x*p01 + q2.y*p02 + q2.z*p12;
                const size_t off = (size_t)(row0 + r) * (3 * G_) + 3 * g;
                out[off + 0] = o0;
                out[off + 1] = o1;
                out[off + 2] = o2;
            }
        }
    }
}

extern "C" void kernel_launch(void* const* d_in, const int* in_sizes, int n_in,
                              void* d_out, int out_size, void* d_ws, size_t ws_size,
                              hipStream_t stream) {
    const float* x    = (const float*)d_in[0];
    const int*   conn = (const int*)d_in[1];
    const float* sel  = (const float*)d_in[2];
    const float* wg   = (const float*)d_in[3];
    float* out  = (float*)d_out;
    float* coef = (float*)d_ws;   // G_*24 floats = 96 KiB

    hipLaunchKernelGGL(fredkin_coef_kernel, dim3(G_ / 256), dim3(256), 0, stream,
                       conn, sel, wg, coef);
    hipLaunchKernelGGL(fredkin_main_kernel, dim3(B_ / (TB * RT)), dim3(TPB), 0, stream,
                       x, conn, coef, out);
}